// Round 1
// 223.061 us; speedup vs baseline: 1.0556x; 1.0556x over previous
//
#include <hip/hip_runtime.h>

// Bilateral denoiser, 1080x1920x11 fp32 -> 1080x1920x3 fp32.
// d^2 <= 36 taps (113). Two y-adjacent pixels per thread packed into
// v_pk_*_f32 lanes (f2). w_normal = med3(dot,0,1)^128 via 7 packed squarings
// (no v_log). w_xy*w_depth = exp2( |dz|*max(invdC*rdz, C*1e4) + lw ) with
// invdC = -log2e/dist and lw = -log2e/2*d^2.
//
// R2: tap loop is now FULLY UNROLLED (j and dx compile-time) and the
// weight table is constexpr (folds to immediates). This removes all
// per-tap s_load_dwordx4 of __constant__ memory from the hot path --
// SMEM and DS share lgkmcnt, and the out-of-order SMEM completions were
// forcing conservative lgkmcnt waits around every tap's ds_read_b128.
// Also kills the 13 runtime scalar guard-branches per j (guards now
// dead-code-eliminate; the surviving 126 taps are identical).
// Tile 32x16, block (32,8), PY=2.

namespace {
constexpr int IMG_H = 1080;
constexpr int IMG_W = 1920;
constexpr int CHN   = 11;
constexpr int TLX   = 32;
constexpr int TLY   = 16;
constexpr int HALO  = 6;
constexpr int RX    = TLX + 2 * HALO;   // 44
constexpr int RY    = TLY + 2 * HALO;   // 28
constexpr int PY    = 2;
constexpr int R2MAX = 36;

constexpr double CD = -1.4426950408889634;   // -log2(e)

struct Tab {
    // [j+6][dx+6] -> {invdC_p0, invdC_p1, lw_p0, lw_p1}; dy_p = j - p
    float v[14][13][4];
    constexpr Tab() : v{} {
        for (int jj = 0; jj < 14; ++jj)
            for (int di = 0; di < 13; ++di)
                for (int p = 0; p < 2; ++p) {
                    const int dy = (jj - 6) - p, dx = di - 6;
                    const int d2 = dy * dy + dx * dx;
                    float ic, lw;
                    if (d2 == 0) {            // center: a==0 anyway; huge -> clamp
                        ic = -1e30f; lw = 0.f;
                    } else if (d2 <= R2MAX) { // active tap
                        double s = (double)d2, x = s;
                        for (int it = 0; it < 60; ++it) x = 0.5 * (x + s / x);
                        ic = (float)(CD / x);
                        lw = (float)(0.5 * CD * d2);
                    } else {                  // pruned/out-of-window: w forced to 0
                        ic = (float)CD; lw = -1e30f;
                    }
                    v[jj][di][p]     = ic;
                    v[jj][di][2 + p] = lw;
                }
    }
};
constexpr Tab TAB{};   // constexpr (NOT __constant__): folds to immediates
}

typedef float f2 __attribute__((ext_vector_type(2)));

__global__ __launch_bounds__(256, 4)
void bilateral_denoise_kernel(const float* __restrict__ in, float* __restrict__ out) {
    __shared__ float4 ldsA[RY * RX];  // {col0, col1, col2, z}
    __shared__ float4 ldsB[RY * RX];  // {nrm0, nrm1, nrm2, 0}

    const int lx  = threadIdx.x;
    const int ty  = threadIdx.y;
    const int bx0 = blockIdx.x * TLX;
    const int by0 = blockIdx.y * TLY;
    const int tid = ty * 32 + lx;

    // ---- stage tile + halo (OOB -> zeros; nrm=0 => c=0 => c^128=0 => w=0) ----
    for (int r = tid; r < RY * RX; r += 256) {
        const int ry = r / RX;
        const int rx = r - ry * RX;
        const int gy = by0 - HALO + ry;
        const int gx = bx0 - HALO + rx;
        float4 A = make_float4(0.f, 0.f, 0.f, 0.f);
        float4 B = make_float4(0.f, 0.f, 0.f, 0.f);
        if ((unsigned)gy < (unsigned)IMG_H && (unsigned)gx < (unsigned)IMG_W) {
            const float* p = in + (gy * IMG_W + gx) * CHN;
            A.x = p[0]; A.y = p[1]; A.z = p[2]; A.w = p[9];
            B.x = p[3]; B.y = p[4]; B.z = p[5];
        }
        ldsA[r] = A;
        ldsB[r] = B;
    }
    __syncthreads();

    // ---- per-pixel-pair center state, packed over p ----
    const int gx = bx0 + lx;
    const int row0 = (ty * PY + HALO) * RX + HALO + lx;
    const float4 A0 = ldsA[row0];
    const float4 A1 = ldsA[row0 + RX];
    const float4 B0 = ldsB[row0];
    const float4 B1 = ldsB[row0 + RX];
    const f2 cnx2 = {B0.x, B1.x};
    const f2 cny2 = {B0.y, B1.y};
    const f2 cnz2 = {B0.z, B1.z};
    const f2 cz2  = {A0.w, A1.w};
    f2 rdz2;
#pragma unroll
    for (int p = 0; p < PY; ++p) {
        const int gy = by0 + ty * PY + p;
        float dzv = 0.f;
        if (gy < IMG_H) dzv = in[(gy * IMG_W + gx) * CHN + 10];
        // dz<=0 -> rcp(0)=+inf -> rrc=-inf -> clamped to C/EPS, matching
        // 1/max(dz*dist, EPS).
        const float rv = __builtin_amdgcn_rcpf(fmaxf(dzv, 0.f));
        if (p == 0) rdz2.x = rv; else rdz2.y = rv;
    }
    f2 accx2 = (f2)(0.f), accy2 = (f2)(0.f), accz2 = (f2)(0.f), accw2 = (f2)(0.f);

    const float RCLAMP = -14426.9504f;   // C_DEPTH * 1e4 (== C/EPS)

    // j = dy + p; FULL unroll: j, dx, table entries all compile-time.
#pragma unroll
    for (int j = -HALO; j <= HALO + 1; ++j) {
        const int dy0 = j, dy1 = j - 1;
        const int m0 = R2MAX - dy0 * dy0;
        const int m1 = R2MAX - dy1 * dy1;
        const int m2 = m0 > m1 ? m0 : m1;
        const int rowb = (ty * PY + HALO + j) * RX + HALO + lx;
#pragma unroll
        for (int dxi = 0; dxi < 13; ++dxi) {
            const int dx = dxi - 6;
            if (dx * dx <= m2) {                    // compile-time guard now
                const f2 invdC = {TAB.v[j + 6][dxi][0], TAB.v[j + 6][dxi][1]};
                const f2 lw2   = {TAB.v[j + 6][dxi][2], TAB.v[j + 6][dxi][3]};
                const float4 A = ldsA[rowb + dx];
                const float4 B = ldsB[rowb + dx];
                // packed over p:
                const f2 dz2  = (f2)(A.w) - cz2;                       // pk_add
                const f2 dot2 = (f2)(B.x) * cnx2 + ((f2)(B.y) * cny2 + (f2)(B.z) * cnz2);
                f2 c2;
                c2.x = fminf(fmaxf(dot2.x, 0.f), 1.f);                 // med3
                c2.y = fminf(fmaxf(dot2.y, 0.f), 1.f);
                f2 s = c2 * c2;                                        // ^128 by
                s = s * s; s = s * s; s = s * s;                       // 7 pk_mul
                s = s * s; s = s * s; s = s * s;
                const f2 rrc = invdC * rdz2;                           // pk_mul
                f2 r2;
                r2.x = fmaxf(rrc.x, RCLAMP);                           // clamp at C/EPS
                r2.y = fmaxf(rrc.y, RCLAMP);
                f2 ad;
                ad.x = fabsf(dz2.x);
                ad.y = fabsf(dz2.y);
                const f2 arg = ad * r2 + lw2;                          // pk_fma
                f2 w2;
                w2.x = __builtin_amdgcn_exp2f(arg.x);
                w2.y = __builtin_amdgcn_exp2f(arg.y);
                w2 *= s;                                               // pk_mul
                accx2 = (f2)(A.x) * w2 + accx2;                        // 4x pk_fma
                accy2 = (f2)(A.y) * w2 + accy2;
                accz2 = (f2)(A.z) * w2 + accz2;
                accw2 += w2;
            }
        }
    }

    // ---- epilogue: out = accum_col / max(accum_w, EPS) ----
#pragma unroll
    for (int p = 0; p < PY; ++p) {
        const int gy = by0 + ty * PY + p;
        if (gy < IMG_H) {
            const float aw = (p == 0) ? accw2.x : accw2.y;
            const float inv = __builtin_amdgcn_rcpf(fmaxf(aw, 1e-4f));
            const int o = (gy * IMG_W + gx) * 3;
            out[o + 0] = ((p == 0) ? accx2.x : accx2.y) * inv;
            out[o + 1] = ((p == 0) ? accy2.x : accy2.y) * inv;
            out[o + 2] = ((p == 0) ? accz2.x : accz2.y) * inv;
        }
    }
}

extern "C" void kernel_launch(void* const* d_in, const int* in_sizes, int n_in,
                              void* d_out, int out_size, void* d_ws, size_t ws_size,
                              hipStream_t stream) {
    const float* in = (const float*)d_in[0];
    float* out = (float*)d_out;
    dim3 grid(IMG_W / TLX, (IMG_H + TLY - 1) / TLY);   // 60 x 68
    dim3 block(32, 8);
    hipLaunchKernelGGL(bilateral_denoise_kernel, grid, block, 0, stream, in, out);
}

// Round 2
// 207.696 us; speedup vs baseline: 1.1337x; 1.0740x over previous
//
#include <hip/hip_runtime.h>

// Bilateral denoiser, 1080x1920x11 fp32 -> 1080x1920x3 fp32.
// d^2 <= 36 taps (113). Two y-adjacent pixels per thread packed into
// v_pk_*_f32 lanes (f2).
//
// R2: w_normal^128 folded into the depth/space exp2 via log-domain:
//   w = exp2( |dz|*max(invdC*rdz, C*1e4) + lw + 128*log2(clamp(dot,0,1)) )
// v_log_f32(0) = -inf -> exp2 -> 0 reproduces clip(dot,EPS,1)^128 (both
// underflow to 0 below ~1e-38); dot>1 clamps to lc=0 -> w_normal=1.
// This deletes the 7 packed squarings + w*=s (8 pk ops = 32 issue cycles
// per tap on SIMD-32, ~1/3 of total issue) and adds 2 v_log (quarter-rate
// trans pipe, issue-port cheap) + 1 pk_fma. fabs folded into VOP3 abs
// modifier of the depth FMA.
// Tap loops fully unrolled, constexpr table folds to immediates (R1).
// Tile 32x16, block (32,8), PY=2.

namespace {
constexpr int IMG_H = 1080;
constexpr int IMG_W = 1920;
constexpr int CHN   = 11;
constexpr int TLX   = 32;
constexpr int TLY   = 16;
constexpr int HALO  = 6;
constexpr int RX    = TLX + 2 * HALO;   // 44
constexpr int RY    = TLY + 2 * HALO;   // 28
constexpr int PY    = 2;
constexpr int R2MAX = 36;

constexpr double CD = -1.4426950408889634;   // -log2(e)

struct Tab {
    // [j+6][dx+6] -> {invdC_p0, invdC_p1, lw_p0, lw_p1}; dy_p = j - p
    float v[14][13][4];
    constexpr Tab() : v{} {
        for (int jj = 0; jj < 14; ++jj)
            for (int di = 0; di < 13; ++di)
                for (int p = 0; p < 2; ++p) {
                    const int dy = (jj - 6) - p, dx = di - 6;
                    const int d2 = dy * dy + dx * dx;
                    float ic, lw;
                    if (d2 == 0) {            // center: a==0 anyway; huge -> clamp
                        ic = -1e30f; lw = 0.f;
                    } else if (d2 <= R2MAX) { // active tap
                        double s = (double)d2, x = s;
                        for (int it = 0; it < 60; ++it) x = 0.5 * (x + s / x);
                        ic = (float)(CD / x);
                        lw = (float)(0.5 * CD * d2);
                    } else {                  // pruned/out-of-window: w forced to 0
                        ic = (float)CD; lw = -1e30f;
                    }
                    v[jj][di][p]     = ic;
                    v[jj][di][2 + p] = lw;
                }
    }
};
constexpr Tab TAB{};   // constexpr (NOT __constant__): folds to immediates
}

typedef float f2 __attribute__((ext_vector_type(2)));

__global__ __launch_bounds__(256, 4)
void bilateral_denoise_kernel(const float* __restrict__ in, float* __restrict__ out) {
    __shared__ float4 ldsA[RY * RX];  // {col0, col1, col2, z}
    __shared__ float4 ldsB[RY * RX];  // {nrm0, nrm1, nrm2, 0}

    const int lx  = threadIdx.x;
    const int ty  = threadIdx.y;
    const int bx0 = blockIdx.x * TLX;
    const int by0 = blockIdx.y * TLY;
    const int tid = ty * 32 + lx;

    // ---- stage tile + halo (OOB -> zeros; nrm=0 => dot=0 => log=-inf => w=0) ----
    for (int r = tid; r < RY * RX; r += 256) {
        const int ry = r / RX;
        const int rx = r - ry * RX;
        const int gy = by0 - HALO + ry;
        const int gx = bx0 - HALO + rx;
        float4 A = make_float4(0.f, 0.f, 0.f, 0.f);
        float4 B = make_float4(0.f, 0.f, 0.f, 0.f);
        if ((unsigned)gy < (unsigned)IMG_H && (unsigned)gx < (unsigned)IMG_W) {
            const float* p = in + (gy * IMG_W + gx) * CHN;
            A.x = p[0]; A.y = p[1]; A.z = p[2]; A.w = p[9];
            B.x = p[3]; B.y = p[4]; B.z = p[5];
        }
        ldsA[r] = A;
        ldsB[r] = B;
    }
    __syncthreads();

    // ---- per-pixel-pair center state, packed over p ----
    const int gx = bx0 + lx;
    const int row0 = (ty * PY + HALO) * RX + HALO + lx;
    const float4 A0 = ldsA[row0];
    const float4 A1 = ldsA[row0 + RX];
    const float4 B0 = ldsB[row0];
    const float4 B1 = ldsB[row0 + RX];
    const f2 cnx2 = {B0.x, B1.x};
    const f2 cny2 = {B0.y, B1.y};
    const f2 cnz2 = {B0.z, B1.z};
    const f2 cz2  = {A0.w, A1.w};
    f2 rdz2;
#pragma unroll
    for (int p = 0; p < PY; ++p) {
        const int gy = by0 + ty * PY + p;
        float dzv = 0.f;
        if (gy < IMG_H) dzv = in[(gy * IMG_W + gx) * CHN + 10];
        // dz<=0 -> rcp(0)=+inf -> rrc=-inf -> clamped to C/EPS, matching
        // 1/max(dz*dist, EPS).
        const float rv = __builtin_amdgcn_rcpf(fmaxf(dzv, 0.f));
        if (p == 0) rdz2.x = rv; else rdz2.y = rv;
    }
    f2 accx2 = (f2)(0.f), accy2 = (f2)(0.f), accz2 = (f2)(0.f), accw2 = (f2)(0.f);

    const float RCLAMP = -14426.9504f;   // C_DEPTH * 1e4 (== C/EPS)

    // j = dy + p; FULL unroll: j, dx, table entries all compile-time.
#pragma unroll
    for (int j = -HALO; j <= HALO + 1; ++j) {
        const int dy0 = j, dy1 = j - 1;
        const int m0 = R2MAX - dy0 * dy0;
        const int m1 = R2MAX - dy1 * dy1;
        const int m2 = m0 > m1 ? m0 : m1;
        const int rowb = (ty * PY + HALO + j) * RX + HALO + lx;
#pragma unroll
        for (int dxi = 0; dxi < 13; ++dxi) {
            const int dx = dxi - 6;
            if (dx * dx <= m2) {                    // compile-time guard
                const f2 invdC = {TAB.v[j + 6][dxi][0], TAB.v[j + 6][dxi][1]};
                const f2 lw2   = {TAB.v[j + 6][dxi][2], TAB.v[j + 6][dxi][3]};
                const float4 A = ldsA[rowb + dx];
                const float4 B = ldsB[rowb + dx];
                // packed over p:
                const f2 dz2  = (f2)(A.w) - cz2;                       // pk_add
                const f2 dot2 = (f2)(B.x) * cnx2 + ((f2)(B.y) * cny2 + (f2)(B.z) * cnz2);
                f2 c2;
                c2.x = fminf(fmaxf(dot2.x, 0.f), 1.f);                 // med3
                c2.y = fminf(fmaxf(dot2.y, 0.f), 1.f);
                f2 lc2;                                                // log2(c): trans pipe
                lc2.x = __builtin_amdgcn_logf(c2.x);                   // log2(0)=-inf -> w=0
                lc2.y = __builtin_amdgcn_logf(c2.y);
                const f2 rrc = invdC * rdz2;                           // pk_mul
                f2 r2;
                r2.x = fmaxf(rrc.x, RCLAMP);                           // clamp at C/EPS
                r2.y = fmaxf(rrc.y, RCLAMP);
                f2 arg;                                                // |dz|: free VOP3 abs mod
                arg.x = fmaf(fabsf(dz2.x), r2.x, lw2.x);
                arg.y = fmaf(fabsf(dz2.y), r2.y, lw2.y);
                const f2 argt = lc2 * 128.f + arg;                     // pk_fma
                f2 w2;
                w2.x = __builtin_amdgcn_exp2f(argt.x);
                w2.y = __builtin_amdgcn_exp2f(argt.y);
                accx2 = (f2)(A.x) * w2 + accx2;                        // 4x pk_fma
                accy2 = (f2)(A.y) * w2 + accy2;
                accz2 = (f2)(A.z) * w2 + accz2;
                accw2 += w2;
            }
        }
    }

    // ---- epilogue: out = accum_col / max(accum_w, EPS) ----
#pragma unroll
    for (int p = 0; p < PY; ++p) {
        const int gy = by0 + ty * PY + p;
        if (gy < IMG_H) {
            const float aw = (p == 0) ? accw2.x : accw2.y;
            const float inv = __builtin_amdgcn_rcpf(fmaxf(aw, 1e-4f));
            const int o = (gy * IMG_W + gx) * 3;
            out[o + 0] = ((p == 0) ? accx2.x : accx2.y) * inv;
            out[o + 1] = ((p == 0) ? accy2.x : accy2.y) * inv;
            out[o + 2] = ((p == 0) ? accz2.x : accz2.y) * inv;
        }
    }
}

extern "C" void kernel_launch(void* const* d_in, const int* in_sizes, int n_in,
                              void* d_out, int out_size, void* d_ws, size_t ws_size,
                              hipStream_t stream) {
    const float* in = (const float*)d_in[0];
    float* out = (float*)d_out;
    dim3 grid(IMG_W / TLX, (IMG_H + TLY - 1) / TLY);   // 60 x 68
    dim3 block(32, 8);
    hipLaunchKernelGGL(bilateral_denoise_kernel, grid, block, 0, stream, in, out);
}